// Round 3
// baseline (318.922 us; speedup 1.0000x reference)
//
#include <hip/hip_runtime.h>
#include <math.h>

#define DIM   256
#define NLVL  5
#define TROWS 32                 // rows per LDS tile
#define BPL   200                // pass1 blocks per level
#define NSB   64                 // stats blocks per level
#define LDSP  257                // padded row stride (floats)

struct Ptrs {
  const float* p[NLVL];
  const float* W[NLVL];
  const float* b[NLVL];
};

// ---- pass 1: LDS-transpose logits. Tile 32 rows; 8-lane group per row. ----
__global__ __launch_bounds__(256) void k_pass1(Ptrs pt, float* __restrict__ logits, int N)
{
  __shared__ float tile[TROWS * LDSP];         // 32.9 KB -> 4 blocks/CU

  const int tid  = threadIdx.x;
  const int lane = tid & 63;
  const int wid  = tid >> 6;
  const int b    = blockIdx.x;
  const int lvl  = b / BPL;                    // 1000 blocks -> 5 levels x 200
  const int bx   = b % BPL;
  const float* __restrict__ p = pt.p[lvl];
  const float* __restrict__ W = pt.W[lvl];
  const float bias = *pt.b[lvl];

  const int e8  = lane & 7;                    // column-eighth within row group
  const int row = (wid << 3) + (lane >> 3);    // tile-local row 0..31

  float4 wreg[8];
  #pragma unroll
  for (int k = 0; k < 8; k++)
    wreg[k] = *reinterpret_cast<const float4*>(W + e8 * 4 + k * 32);

  const int ntile = N / TROWS;                 // 3125
  for (int t = bx; t < ntile; t += BPL) {
    const int tt = ntile - 1 - t;              // descending: ride L3 residue of pass2
    const size_t n0 = (size_t)tt * TROWS;

    // stage: 8 co-resident float4 loads per thread (issued before the barrier,
    // so they overlap the previous tile's compute phase)
    float4 r[8];
    const float* src = p + n0 * DIM + tid * 4;
    #pragma unroll
    for (int j = 0; j < 8; j++)
      r[j] = *reinterpret_cast<const float4*>(src + j * 1024);   // f = j*256 + tid

    __syncthreads();                           // previous compute done
    #pragma unroll
    for (int j = 0; j < 8; j++) {
      const int f = j * 256 + tid;             // flat float4 index in 32x256 tile
      const int rw = f >> 6, c4 = (f & 63) << 2;
      *reinterpret_cast<float4*>(&tile[rw * LDSP + c4]) = r[j];
    }
    __syncthreads();

    // compute: 8 ds_read_b128 + 32 FMA per thread, 3 small-mask shuffles
    float acc = 0.f;
    #pragma unroll
    for (int k = 0; k < 8; k++) {
      float4 a = *reinterpret_cast<const float4*>(&tile[row * LDSP + e8 * 4 + k * 32]);
      float4 w = wreg[k];
      acc += a.x * w.x + a.y * w.y + a.z * w.z + a.w * w.w;
    }
    acc += __shfl_xor(acc, 4);
    acc += __shfl_xor(acc, 2);
    acc += __shfl_xor(acc, 1);
    if (e8 == 0)                               // 8 lanes -> 8 consecutive floats
      logits[(size_t)lvl * N + n0 + row] = acc + bias;
  }
}

// ---- stats A: per-(level,block) online-softmax partials over logits ----
__global__ __launch_bounds__(256) void k_stats(const float* __restrict__ logits,
                                               float2* __restrict__ part, int N)
{
  const int lvl = blockIdx.y;
  const float* __restrict__ lg = logits + (size_t)lvl * N;
  float m = -INFINITY, s = 0.f;
  for (int i = blockIdx.x * 256 + threadIdx.x; i < N; i += NSB * 256) {
    float d  = lg[i];
    float Mn = fmaxf(m, d);
    s = s * __expf(m - Mn) + __expf(d - Mn);
    m = Mn;
  }
  const int lane = threadIdx.x & 63;
  const int wid  = threadIdx.x >> 6;
  #pragma unroll
  for (int off = 32; off; off >>= 1) {
    float mo = __shfl_xor(m, off), so = __shfl_xor(s, off);
    float Mn = fmaxf(m, mo);
    if (Mn > -INFINITY) { s = s * __expf(m - Mn) + so * __expf(mo - Mn); m = Mn; }
  }
  __shared__ float smM[4], smS[4];
  if (lane == 0) { smM[wid] = m; smS[wid] = s; }
  __syncthreads();
  if (threadIdx.x == 0) {
    float M = smM[0], S = smS[0];
    #pragma unroll
    for (int i = 1; i < 4; i++) {
      float Mn = fmaxf(M, smM[i]);
      if (Mn > -INFINITY) { S = S * __expf(M - Mn) + smS[i] * __expf(smM[i] - Mn); M = Mn; }
    }
    part[lvl * NSB + blockIdx.x] = make_float2(M, S);
  }
}

// ---- stats B: combine NSB partials per level -> (M, S) ----
__global__ __launch_bounds__(320) void k_reduce(const float2* __restrict__ part,
                                                float2* __restrict__ stats)
{
  const int lvl  = threadIdx.x >> 6;
  const int lane = threadIdx.x & 63;
  float m = -INFINITY, s = 0.f;
  if (lane < NSB) { float2 ps = part[lvl * NSB + lane]; m = ps.x; s = ps.y; }
  #pragma unroll
  for (int off = 32; off; off >>= 1) {
    float mo = __shfl_xor(m, off), so = __shfl_xor(s, off);
    float Mn = fmaxf(m, mo);
    if (Mn > -INFINITY) { s = s * __expf(m - Mn) + so * __expf(mo - Mn); m = Mn; }
  }
  if (lane == 0) stats[lvl] = make_float2(m, s);
}

// ---- pass 2: weights + fused output (ascending n) ----
__global__ __launch_bounds__(256) void k_pass2(Ptrs pt, const float* __restrict__ logits,
                                               const float2* __restrict__ stats,
                                               float* __restrict__ out, int N)
{
  const int lane = threadIdx.x & 63;
  const int wid  = threadIdx.x >> 6;
  float M[NLVL], Si[NLVL];
  #pragma unroll
  for (int l = 0; l < NLVL; l++) { float2 st = stats[l]; M[l] = st.x; Si[l] = 1.f / st.y; }

  const int gw = blockIdx.x * 4 + wid;
  const int nw = gridDim.x * 4;
  for (int n = gw; n < N; n += nw) {
    float wl[NLVL], t = 0.f;
    #pragma unroll
    for (int l = 0; l < NLVL; l++) {
      float e = __expf(logits[(size_t)l * N + n] - M[l]) * Si[l];
      wl[l] = e; t += e;
    }
    const float inv = 1.f / t;
    float4 acc = make_float4(0.f, 0.f, 0.f, 0.f);
    #pragma unroll
    for (int l = 0; l < NLVL; l++) {
      float4 pv = *reinterpret_cast<const float4*>(pt.p[l] + (size_t)n * DIM + lane * 4);
      float c = wl[l] * inv;
      acc.x += c * pv.x; acc.y += c * pv.y; acc.z += c * pv.z; acc.w += c * pv.w;
    }
    *reinterpret_cast<float4*>(out + (size_t)n * DIM + lane * 4) = acc;
  }
}

extern "C" void kernel_launch(void* const* d_in, const int* in_sizes, int n_in,
                              void* d_out, int out_size, void* d_ws, size_t ws_size,
                              hipStream_t stream)
{
  Ptrs pt;
  for (int l = 0; l < NLVL; l++) {
    pt.p[l] = (const float*)d_in[l];
    pt.W[l] = (const float*)d_in[5 + 2 * l];
    pt.b[l] = (const float*)d_in[6 + 2 * l];
  }
  const int N = in_sizes[0] / DIM;             // 100000

  char* ws = (char*)d_ws;
  size_t logits_bytes = ((size_t)NLVL * N * sizeof(float) + 255) & ~(size_t)255;
  float*  logits = (float*)ws;
  float2* part   = (float2*)(ws + logits_bytes);
  float2* stats  = part + NLVL * NSB;

  k_pass1 <<<NLVL * BPL,        256, 0, stream>>>(pt, logits, N);
  k_stats <<<dim3(NSB, NLVL),   256, 0, stream>>>(logits, part, N);
  k_reduce<<<1,                 320, 0, stream>>>(part, stats);
  k_pass2 <<<2048,              256, 0, stream>>>(pt, logits, stats, (float*)d_out, N);
}

// Round 4
// 226.657 us; speedup vs baseline: 1.4071x; 1.4071x over previous
//
#include <hip/hip_runtime.h>
#include <math.h>

#define DIM   256
#define NLVL  5
#define NB1   1024   // pass1 blocks
#define NW1   (NB1*4)

struct Ptrs {
  const float* p[NLVL];
  const float* W[NLVL];
  const float* b[NLVL];
};

// ---- pass 1: all 5 levels per row (MLP=5, mirrors pass2's load shape),
//      fused online-softmax partials. Iterates n DESCENDING for L3 reuse.
__global__ __launch_bounds__(256) void k_pass1(Ptrs pt, float* __restrict__ logits,
                                               float2* __restrict__ part, int N)
{
  const int lane = threadIdx.x & 63;
  const int wid  = threadIdx.x >> 6;

  float4 wf[NLVL];
  float  bias[NLVL], m[NLVL], s[NLVL];
  #pragma unroll
  for (int l = 0; l < NLVL; l++) {
    wf[l]   = *reinterpret_cast<const float4*>(pt.W[l] + lane * 4);
    bias[l] = *pt.b[l];
    m[l]    = -INFINITY;
    s[l]    = 0.f;
  }

  const int gw = blockIdx.x * 4 + wid;
  for (int i = gw; i < N; i += NW1) {
    const int n = N - 1 - i;                   // descending: ride pass2's L3 residue
    float d[NLVL];
    #pragma unroll
    for (int l = 0; l < NLVL; l++) {           // 5 independent 1KB wave-loads
      float4 pv = *reinterpret_cast<const float4*>(pt.p[l] + (size_t)n * DIM + lane * 4);
      d[l] = pv.x * wf[l].x + pv.y * wf[l].y + pv.z * wf[l].z + pv.w * wf[l].w;
    }
    #pragma unroll
    for (int off = 32; off; off >>= 1) {       // 5 independent reduce chains (ILP-5)
      #pragma unroll
      for (int l = 0; l < NLVL; l++) d[l] += __shfl_xor(d[l], off);
    }
    #pragma unroll
    for (int l = 0; l < NLVL; l++) {
      d[l] += bias[l];
      if (lane == l) logits[(size_t)l * N + n] = d[l];   // one store, 5-lane exec mask
      float Mn = fmaxf(m[l], d[l]);            // online update (lane-redundant, cheap)
      s[l] = s[l] * __expf(m[l] - Mn) + __expf(d[l] - Mn);
      m[l] = Mn;
    }
  }

  __shared__ float smM[4][NLVL], smS[4][NLVL];
  if (lane == 0) {
    #pragma unroll
    for (int l = 0; l < NLVL; l++) { smM[wid][l] = m[l]; smS[wid][l] = s[l]; }
  }
  __syncthreads();
  if (threadIdx.x < NLVL) {                    // thread l combines 4 waves for level l
    const int l = threadIdx.x;
    float M = smM[0][l], S = smS[0][l];
    #pragma unroll
    for (int i = 1; i < 4; i++) {
      float Mn = fmaxf(M, smM[i][l]);
      if (Mn > -INFINITY) { S = S * __expf(M - Mn) + smS[i][l] * __expf(smM[i][l] - Mn); M = Mn; }
    }
    part[l * NB1 + blockIdx.x] = make_float2(M, S);
  }
}

// ---- combine NB1 partials per level -> (M, S) ----
__global__ __launch_bounds__(320) void k_reduce(const float2* __restrict__ part,
                                                float2* __restrict__ stats)
{
  const int lvl  = threadIdx.x >> 6;           // 5 waves, one per level
  const int lane = threadIdx.x & 63;
  float m = -INFINITY, s = 0.f;
  for (int i = lane; i < NB1; i += 64) {
    float2 ps = part[lvl * NB1 + i];
    float Mn = fmaxf(m, ps.x);
    if (Mn > -INFINITY) { s = s * __expf(m - Mn) + ps.y * __expf(ps.x - Mn); m = Mn; }
  }
  #pragma unroll
  for (int off = 32; off; off >>= 1) {
    float mo = __shfl_xor(m, off), so = __shfl_xor(s, off);
    float Mn = fmaxf(m, mo);
    if (Mn > -INFINITY) { s = s * __expf(m - Mn) + so * __expf(mo - Mn); m = Mn; }
  }
  if (lane == 0) stats[lvl] = make_float2(m, s);
}

// ---- pass 2: weights + fused output (ascending n) ----
__global__ __launch_bounds__(256) void k_pass2(Ptrs pt, const float* __restrict__ logits,
                                               const float2* __restrict__ stats,
                                               float* __restrict__ out, int N)
{
  const int lane = threadIdx.x & 63;
  const int wid  = threadIdx.x >> 6;
  float M[NLVL], Si[NLVL];
  #pragma unroll
  for (int l = 0; l < NLVL; l++) { float2 st = stats[l]; M[l] = st.x; Si[l] = 1.f / st.y; }

  const int gw = blockIdx.x * 4 + wid;
  const int nw = gridDim.x * 4;
  for (int n = gw; n < N; n += nw) {
    float wl[NLVL], t = 0.f;
    #pragma unroll
    for (int l = 0; l < NLVL; l++) {
      float e = __expf(logits[(size_t)l * N + n] - M[l]) * Si[l];
      wl[l] = e; t += e;
    }
    const float inv = 1.f / t;
    float4 acc = make_float4(0.f, 0.f, 0.f, 0.f);
    #pragma unroll
    for (int l = 0; l < NLVL; l++) {
      float4 pv = *reinterpret_cast<const float4*>(pt.p[l] + (size_t)n * DIM + lane * 4);
      float c = wl[l] * inv;
      acc.x += c * pv.x; acc.y += c * pv.y; acc.z += c * pv.z; acc.w += c * pv.w;
    }
    *reinterpret_cast<float4*>(out + (size_t)n * DIM + lane * 4) = acc;
  }
}

extern "C" void kernel_launch(void* const* d_in, const int* in_sizes, int n_in,
                              void* d_out, int out_size, void* d_ws, size_t ws_size,
                              hipStream_t stream)
{
  Ptrs pt;
  for (int l = 0; l < NLVL; l++) {
    pt.p[l] = (const float*)d_in[l];
    pt.W[l] = (const float*)d_in[5 + 2 * l];
    pt.b[l] = (const float*)d_in[6 + 2 * l];
  }
  const int N = in_sizes[0] / DIM;             // 100000

  char* ws = (char*)d_ws;
  size_t logits_bytes = ((size_t)NLVL * N * sizeof(float) + 255) & ~(size_t)255;
  float*  logits = (float*)ws;
  float2* part   = (float2*)(ws + logits_bytes);
  float2* stats  = part + NLVL * NB1;

  k_pass1 <<<NB1,  256, 0, stream>>>(pt, logits, part, N);
  k_reduce<<<1,    320, 0, stream>>>(part, stats);
  k_pass2 <<<2048, 256, 0, stream>>>(pt, logits, stats, (float*)d_out, N);
}